// Round 9
// baseline (142.486 us; speedup 1.0000x reference)
//
#include <hip/hip_runtime.h>
#include <hip/hip_bf16.h>

// Word2MatEncoder: out[b] = prod_{t=0..63} lookup_weight[sent[b,t]] (28x28 chain)
//
// Kernel 1 (w2m_partial_mfma): 4096 one-wave blocks (256 batch x 16 seg, 4
//   matrices per segment). TRANSPOSED iteration S_t^T = M_t^T * S_{t-1}^T via
//   v_mfma_f32_32x32x16_bf16; f32 emulated by exact truncation split
//   x = hi + lo (3 cross terms x 2 K-halves = 6 MFMA/step).
//   VERIFIED (R4/R5/R6, absmax 32): A/B layout m,n = lane&31, k = 16K+8h+e
//   (h = lane>>5); C/D layout col = lane&31, row = (e&3)+8*(e>>2)+4h.
//   R6 was LDS-pipe/latency-bound (48 ds ops/step + D->LDS->A round-trip on
//   the serial chain). This round kernel1 uses ZERO LDS:
//     - Running product is the B operand; D->B relayout is a pure half-wave
//       exchange: bb[K*8+e'] = ((e'>>2)==h) ? d[(e'&3)+4h+8K]
//                                           : shfl_xor(d[(e'&3)+4h+8K], 32).
//       (16 __shfl_xor + 16 cndmask, all static indices, no inline asm.)
//     - A = M_t^T straight from global: lane m reads M_t[k][m] (coalesced
//       128B per k), rows k>=28 zeroed (kills all pad garbage), lane clamp
//       m->27 keeps last-table-row reads in bounds. 1-step reg prefetch.
//
// Kernel 2 (w2m_combine): unchanged (verified R6): 16-partial tree, 512 thr.
//   Buffer contract (unchanged): even seg buf = P^T row-major (A-side),
//   odd seg buf = P row-major (B-side). Kernel1's D = P^T, so the two store
//   branches are swapped relative to R6 to keep the bytes identical.

typedef float f32x4  __attribute__((ext_vector_type(4)));
typedef float f32x16 __attribute__((ext_vector_type(16)));
typedef short bf16x8 __attribute__((ext_vector_type(8)));

namespace {
constexpr int MD  = 28;
constexpr int EMB = 784;
constexpr int SEQ = 64;
constexpr int BATCH = 256;
constexpr int SEG = 16;  // segments per batch
constexpr int LEN = 4;   // matrices per segment
}

__device__ __forceinline__ bf16x8 mkfrag(uint32_t w0, uint32_t w1,
                                         uint32_t w2, uint32_t w3) {
  union { uint32_t w[4]; bf16x8 b; } u;
  u.w[0] = w0; u.w[1] = w1; u.w[2] = w2; u.w[3] = w3;
  return u.b;
}

// 8 f32 -> hi/lo bf16 fragments. Truncation split: hi = x & 0xffff0000 (exact
// bf16), lo = x - hi (exact), lo truncated to bf16.
__device__ __forceinline__ void split8(const float* x, bf16x8& hi, bf16x8& lo) {
  uint32_t H[4], L[4];
#pragma unroll
  for (int p = 0; p < 4; ++p) {
    float x0 = x[2 * p], x1 = x[2 * p + 1];
    uint32_t h0 = __float_as_uint(x0) & 0xffff0000u;
    uint32_t h1 = __float_as_uint(x1) & 0xffff0000u;
    float l0 = x0 - __uint_as_float(h0);
    float l1 = x1 - __uint_as_float(h1);
    H[p] = (h0 >> 16) | h1;
    L[p] = (__float_as_uint(l0) >> 16) | (__float_as_uint(l1) & 0xffff0000u);
  }
  hi = mkfrag(H[0], H[1], H[2], H[3]);
  lo = mkfrag(L[0], L[1], L[2], L[3]);
}

__global__ __launch_bounds__(64)
__attribute__((amdgpu_waves_per_eu(3, 4)))
void w2m_partial_mfma(const int* __restrict__ sent,
                      const float* __restrict__ W,
                      float* __restrict__ ws) {
  const int blk   = blockIdx.x;
  const int batch = blk >> 4;
  const int seg   = blk & 15;
  const int lane  = threadIdx.x;
  const int n  = lane & 31;          // A-row m / B-col n / D-col
  const int h  = lane >> 5;
  const int nc = n < 27 ? n : 27;    // address clamp (contents are don't-care)
  const int* srow = sent + batch * SEQ + seg * LEN;

  // A fragments of M_t^T: a[K*8+e] = M_t[k][nc], k = 16K+8h+e; 0 for k>=28.
  // For fixed k, lanes read consecutive floats -> coalesced.
  auto loadA = [&](int t, float* a) {
    const float* __restrict__ Mt = W + (size_t)srow[t] * EMB;
#pragma unroll
    for (int K = 0; K < 2; ++K)
#pragma unroll
      for (int e = 0; e < 8; ++e) {
        int k = 16 * K + 8 * h + e;
        float v = 0.f;
        if (k < MD) v = Mt[k * MD + nc];   // predicated: no OOB, zeros pad
        a[K * 8 + e] = v;
      }
  };

  // B0 = M0^T-as-B: b[K*8+e] = M0[n][k], k = 16K+8h+e; row-contiguous f32x4.
  float b0[16];
  {
    const float* __restrict__ M0 = W + (size_t)srow[0] * EMB;
#pragma unroll
    for (int K = 0; K < 2; ++K)
#pragma unroll
      for (int u = 0; u < 2; ++u) {
        int k0 = 16 * K + 8 * h + 4 * u;
        f32x4 v = {0.f, 0.f, 0.f, 0.f};
        if (k0 < MD)                        // only (K=1,h=1,u=1) masked out
          v = *reinterpret_cast<const f32x4*>(M0 + nc * MD + k0);
        b0[K * 8 + 4 * u + 0] = v[0];
        b0[K * 8 + 4 * u + 1] = v[1];
        b0[K * 8 + 4 * u + 2] = v[2];
        b0[K * 8 + 4 * u + 3] = v[3];
      }
  }

  float a_cur[16], a_nxt[16];
  loadA(1, a_cur);
  loadA(2, a_nxt);

  bf16x8 bh0, bl0, bh1, bl1;
  split8(b0,     bh0, bl0);
  split8(b0 + 8, bh1, bl1);

  f32x16 d;
#pragma unroll
  for (int t = 1; t < LEN; ++t) {
    bf16x8 ah0, al0, ah1, al1;
    split8(a_cur,     ah0, al0);
    split8(a_cur + 8, ah1, al1);
    if (t + 1 < LEN) {
#pragma unroll
      for (int q = 0; q < 16; ++q) a_cur[q] = a_nxt[q];
      if (t + 2 < LEN) loadA(t + 2, a_nxt);
    }

#pragma unroll
    for (int q = 0; q < 16; ++q) d[q] = 0.f;
    d = __builtin_amdgcn_mfma_f32_32x32x16_bf16(ah0, bh0, d, 0, 0, 0);
    d = __builtin_amdgcn_mfma_f32_32x32x16_bf16(ah0, bl0, d, 0, 0, 0);
    d = __builtin_amdgcn_mfma_f32_32x32x16_bf16(al0, bh0, d, 0, 0, 0);
    d = __builtin_amdgcn_mfma_f32_32x32x16_bf16(ah1, bh1, d, 0, 0, 0);
    d = __builtin_amdgcn_mfma_f32_32x32x16_bf16(ah1, bl1, d, 0, 0, 0);
    d = __builtin_amdgcn_mfma_f32_32x32x16_bf16(al1, bh1, d, 0, 0, 0);

    if (t < LEN - 1) {
      // D (rows r=(e&3)+8(e>>2)+4h) -> B frags (rows k=16K+8h+e'), pure
      // register/cross-lane exchange; all indices compile-time static.
      float s_[16];
#pragma unroll
      for (int e = 0; e < 16; ++e) s_[e] = __shfl_xor((float)d[e], 32);
      float bb[16];
#pragma unroll
      for (int K = 0; K < 2; ++K)
#pragma unroll
        for (int e = 0; e < 4; ++e) {
          // e' = e   (e'>>2 == 0): own half iff h==0
          bb[K * 8 + e]     = h ? s_[e + 4 + 8 * K] : (float)d[e + 8 * K];
          // e' = e+4 (e'>>2 == 1): own half iff h==1
          bb[K * 8 + e + 4] = h ? (float)d[e + 4 + 8 * K] : s_[e + 8 * K];
        }
      split8(bb,     bh0, bl0);
      split8(bb + 8, bh1, bl1);
    }
  }

  // D = (M_seg0*...*M_seg3)^T = P^T: d[e] = P^T[r][n], r=(e&3)+8(e>>2)+4h.
  // even seg -> buf = P^T row-major (A-side): pb[r*28+n] = d[e]
  // odd  seg -> buf = P row-major (B-side):   pb[n*28+r] = d[e] (f32x4 runs)
  float* pb = ws + (size_t)(batch * SEG + seg) * EMB;
  if (n < MD) {
    if ((seg & 1) == 0) {
#pragma unroll
      for (int e = 0; e < 16; ++e) {
        int r = (e & 3) + 8 * (e >> 2) + 4 * h;
        if (r < MD) pb[r * MD + n] = d[e];
      }
    } else {
#pragma unroll
      for (int q = 0; q < 4; ++q) {
        int r0 = 8 * q + 4 * h;
        if (r0 < MD) {
          f32x4 v = { d[4 * q], d[4 * q + 1], d[4 * q + 2], d[4 * q + 3] };
          *reinterpret_cast<f32x4*>(pb + n * MD + r0) = v;
        }
      }
    }
  }
}

// ---------------- kernel 2: tree-combine 16 partials (verified R6) --------

__device__ __forceinline__ void kloop(const float* __restrict__ A,
                                      const float* __restrict__ B,
                                      int r0, int c0,
                                      f32x4& a0, f32x4& a1, f32x4& a2, f32x4& a3) {
  f32x4 z = {0.f, 0.f, 0.f, 0.f};
  a0 = a1 = a2 = a3 = z;
#pragma unroll
  for (int k = 0; k < MD; ++k) {
    f32x4 rv = *reinterpret_cast<const f32x4*>(A + k * MD + r0);
    f32x4 mv = *reinterpret_cast<const f32x4*>(B + k * MD + c0);
    a0 += rv[0] * mv;
    a1 += rv[1] * mv;
    a2 += rv[2] * mv;
    a3 += rv[3] * mv;
  }
}

__device__ __forceinline__ void store_T(float* __restrict__ D, int r0, int c0,
                                        const f32x4& a0, const f32x4& a1,
                                        const f32x4& a2, const f32x4& a3) {
#pragma unroll
  for (int cc = 0; cc < 4; ++cc) {
    f32x4 v = { a0[cc], a1[cc], a2[cc], a3[cc] };
    *reinterpret_cast<f32x4*>(D + (c0 + cc) * MD + r0) = v;
  }
}

__device__ __forceinline__ void store_N(float* __restrict__ D, int r0, int c0,
                                        const f32x4& a0, const f32x4& a1,
                                        const f32x4& a2, const f32x4& a3) {
  *reinterpret_cast<f32x4*>(D + (r0 + 0) * MD + c0) = a0;
  *reinterpret_cast<f32x4*>(D + (r0 + 1) * MD + c0) = a1;
  *reinterpret_cast<f32x4*>(D + (r0 + 2) * MD + c0) = a2;
  *reinterpret_cast<f32x4*>(D + (r0 + 3) * MD + c0) = a3;
}

__global__ __launch_bounds__(512, 1)
void w2m_combine(const float* __restrict__ ws, float* __restrict__ out) {
  __shared__ __align__(16) float P[SEG][EMB];
  __shared__ __align__(16) float Q8[8][EMB];
  __shared__ __align__(16) float Q4[4][EMB];
  __shared__ __align__(16) float Q2[2][EMB];

  const int batch = blockIdx.x;
  const int tid   = threadIdx.x;
  const int w     = tid >> 6;       // 0..7
  const int lane  = tid & 63;
  const bool act  = lane < 49;
  const int i = lane / 7, j = lane % 7;
  const int r0 = 4 * i, c0 = 4 * j;

  {
    const f32x4* src = reinterpret_cast<const f32x4*>(ws + (size_t)batch * SEG * EMB);
    f32x4* dst = reinterpret_cast<f32x4*>(&P[0][0]);
    for (int u = tid; u < SEG * EMB / 4; u += 512) dst[u] = src[u];
  }
  __syncthreads();

  f32x4 a0, a1, a2, a3;
  // level 0: Q8[w] = P[2w] * P[2w+1]   (8 waves)
  if (act) {
    kloop(P[2 * w], P[2 * w + 1], r0, c0, a0, a1, a2, a3);
    if (w & 1) store_N(Q8[w], r0, c0, a0, a1, a2, a3);
    else       store_T(Q8[w], r0, c0, a0, a1, a2, a3);
  }
  __syncthreads();
  // level 1: Q4[w] = Q8[2w] * Q8[2w+1]  (4 waves)
  if (w < 4 && act) {
    kloop(Q8[2 * w], Q8[2 * w + 1], r0, c0, a0, a1, a2, a3);
    if (w & 1) store_N(Q4[w], r0, c0, a0, a1, a2, a3);
    else       store_T(Q4[w], r0, c0, a0, a1, a2, a3);
  }
  __syncthreads();
  // level 2: Q2[w] = Q4[2w] * Q4[2w+1]  (2 waves)
  if (w < 2 && act) {
    kloop(Q4[2 * w], Q4[2 * w + 1], r0, c0, a0, a1, a2, a3);
    if (w & 1) store_N(Q2[w], r0, c0, a0, a1, a2, a3);
    else       store_T(Q2[w], r0, c0, a0, a1, a2, a3);
  }
  __syncthreads();
  // level 3: out = Q2[0] * Q2[1]
  if (w == 0 && act) {
    kloop(Q2[0], Q2[1], r0, c0, a0, a1, a2, a3);
    store_N(out + (size_t)batch * EMB, r0, c0, a0, a1, a2, a3);
  }
}

extern "C" void kernel_launch(void* const* d_in, const int* in_sizes, int n_in,
                              void* d_out, int out_size, void* d_ws, size_t ws_size,
                              hipStream_t stream) {
  const int*   sent = (const int*)d_in[0];    // (256, 64) int32
  const float* W    = (const float*)d_in[1];  // (30001, 784) f32
  float*       out  = (float*)d_out;          // (256, 784) f32
  float*       ws   = (float*)d_ws;           // 256*16*784*4 = 12.8 MB
  (void)in_sizes; (void)n_in; (void)out_size; (void)ws_size;

  w2m_partial_mfma<<<BATCH * SEG, 64, 0, stream>>>(sent, W, ws);
  w2m_combine<<<BATCH, 512, 0, stream>>>(ws, out);
}

// Round 11
// 141.445 us; speedup vs baseline: 1.0074x; 1.0074x over previous
//
#include <hip/hip_runtime.h>
#include <hip/hip_bf16.h>

// Word2MatEncoder: out[b] = prod_{t=0..63} lookup_weight[sent[b,t]] (28x28 chain)
//
// Kernel 1 (w2m_partial_mfma): 4096 one-wave blocks (256 batch x 16 seg, 4
//   matrices per segment). TRANSPOSED iteration S_t^T = M_t^T * S_{t-1}^T via
//   v_mfma_f32_32x32x16_bf16; f32 emulated by exact truncation split
//   x = hi + lo (3 cross terms x 2 K-halves = 6 MFMA/step). ZERO LDS.
//   VERIFIED (R4..R9, absmax 32): A/B layout m,n = lane&31, k = 16K+8h+e
//   (h = lane>>5); C/D layout col = lane&31, row = (e&3)+8*(e>>2)+4h;
//   D->B relayout = half-wave exchange (16 shfl_xor(32) + cndmask).
//   R9 post-mortem: dur unchanged vs R6 -> kernel1 still ~20us. Suspected
//   scratch spills: amdgpu_waves_per_eu(3,4) caps VGPR at ~160; R9's live
//   state (~140 f32 + temps) crosses it (R4 pathology at a higher cap).
//   This round:
//     - __launch_bounds__(64, 1): min 1 wave/EU -> VGPR cap 512, NO spills.
//     - A-prefetch kept as bf16 fragments (split at load): removes the
//       a_cur[16] f32 copy (-16 live regs, -16 movs/step).
//
// Kernel 2 (w2m_combine): unchanged (verified R6/R9): 16-partial tree.
//   Buffer contract: even seg buf = P^T row-major (A-side), odd seg buf = P
//   row-major (B-side).

typedef float f32x4  __attribute__((ext_vector_type(4)));
typedef float f32x16 __attribute__((ext_vector_type(16)));
typedef short bf16x8 __attribute__((ext_vector_type(8)));

namespace {
constexpr int MD  = 28;
constexpr int EMB = 784;
constexpr int SEQ = 64;
constexpr int BATCH = 256;
constexpr int SEG = 16;  // segments per batch
constexpr int LEN = 4;   // matrices per segment
}

__device__ __forceinline__ bf16x8 mkfrag(uint32_t w0, uint32_t w1,
                                         uint32_t w2, uint32_t w3) {
  union { uint32_t w[4]; bf16x8 b; } u;
  u.w[0] = w0; u.w[1] = w1; u.w[2] = w2; u.w[3] = w3;
  return u.b;
}

// 8 f32 -> hi/lo bf16 fragments. Truncation split: hi = x & 0xffff0000 (exact
// bf16), lo = x - hi (exact), lo truncated to bf16.
__device__ __forceinline__ void split8(const float* x, bf16x8& hi, bf16x8& lo) {
  uint32_t H[4], L[4];
#pragma unroll
  for (int p = 0; p < 4; ++p) {
    float x0 = x[2 * p], x1 = x[2 * p + 1];
    uint32_t h0 = __float_as_uint(x0) & 0xffff0000u;
    uint32_t h1 = __float_as_uint(x1) & 0xffff0000u;
    float l0 = x0 - __uint_as_float(h0);
    float l1 = x1 - __uint_as_float(h1);
    H[p] = (h0 >> 16) | h1;
    L[p] = (__float_as_uint(l0) >> 16) | (__float_as_uint(l1) & 0xffff0000u);
  }
  hi = mkfrag(H[0], H[1], H[2], H[3]);
  lo = mkfrag(L[0], L[1], L[2], L[3]);
}

__global__ __launch_bounds__(64, 1)
void w2m_partial_mfma(const int* __restrict__ sent,
                      const float* __restrict__ W,
                      float* __restrict__ ws) {
  const int blk   = blockIdx.x;
  const int batch = blk >> 4;
  const int seg   = blk & 15;
  const int lane  = threadIdx.x;
  const int n  = lane & 31;          // A-row m / B-col n / D-col
  const int h  = lane >> 5;
  const int nc = n < 27 ? n : 27;    // address clamp (contents are don't-care)
  const int* srow = sent + batch * SEQ + seg * LEN;

  // A fragments of M_t^T, split to bf16 hi/lo at load time.
  // F[0]=ah0 F[1]=al0 F[2]=ah1 F[3]=al1 (all indices compile-time).
  auto loadA_frags = [&](int t, bf16x8* F) {
    const float* __restrict__ Mt = W + (size_t)srow[t] * EMB;
    float tmp[16];
#pragma unroll
    for (int K = 0; K < 2; ++K)
#pragma unroll
      for (int e = 0; e < 8; ++e) {
        int k = 16 * K + 8 * h + e;
        float v = 0.f;
        if (k < MD) v = Mt[k * MD + nc];   // predicated: no OOB, zeros pad
        tmp[K * 8 + e] = v;
      }
    split8(tmp,     F[0], F[1]);
    split8(tmp + 8, F[2], F[3]);
  };

  // B0 = M0^T-as-B: b[K*8+e] = M0[n][k], k = 16K+8h+e; row-contiguous f32x4.
  bf16x8 bF[4];   // bh0, bl0, bh1, bl1
  {
    float b0[16];
    const float* __restrict__ M0 = W + (size_t)srow[0] * EMB;
#pragma unroll
    for (int K = 0; K < 2; ++K)
#pragma unroll
      for (int u = 0; u < 2; ++u) {
        int k0 = 16 * K + 8 * h + 4 * u;
        f32x4 v = {0.f, 0.f, 0.f, 0.f};
        if (k0 < MD)                        // only (K=1,h=1,u=1) masked out
          v = *reinterpret_cast<const f32x4*>(M0 + nc * MD + k0);
        b0[K * 8 + 4 * u + 0] = v[0];
        b0[K * 8 + 4 * u + 1] = v[1];
        b0[K * 8 + 4 * u + 2] = v[2];
        b0[K * 8 + 4 * u + 3] = v[3];
      }
    split8(b0,     bF[0], bF[1]);
    split8(b0 + 8, bF[2], bF[3]);
  }

  bf16x8 aC[4], aN[4];
  loadA_frags(1, aC);
  loadA_frags(2, aN);

  f32x16 d;
#pragma unroll
  for (int t = 1; t < LEN; ++t) {
#pragma unroll
    for (int q = 0; q < 16; ++q) d[q] = 0.f;
    d = __builtin_amdgcn_mfma_f32_32x32x16_bf16(aC[0], bF[0], d, 0, 0, 0);
    d = __builtin_amdgcn_mfma_f32_32x32x16_bf16(aC[0], bF[1], d, 0, 0, 0);
    d = __builtin_amdgcn_mfma_f32_32x32x16_bf16(aC[1], bF[0], d, 0, 0, 0);
    d = __builtin_amdgcn_mfma_f32_32x32x16_bf16(aC[2], bF[2], d, 0, 0, 0);
    d = __builtin_amdgcn_mfma_f32_32x32x16_bf16(aC[2], bF[3], d, 0, 0, 0);
    d = __builtin_amdgcn_mfma_f32_32x32x16_bf16(aC[3], bF[2], d, 0, 0, 0);

    if (t + 1 < LEN) {
      aC[0] = aN[0]; aC[1] = aN[1]; aC[2] = aN[2]; aC[3] = aN[3];
      if (t + 2 < LEN) loadA_frags(t + 2, aN);
    }

    if (t < LEN - 1) {
      // D (rows r=(e&3)+8(e>>2)+4h) -> B frags (rows k=16K+8h+e'), pure
      // register/cross-lane exchange; all indices compile-time static.
      // (verified R9)
      float s_[16];
#pragma unroll
      for (int e = 0; e < 16; ++e) s_[e] = __shfl_xor((float)d[e], 32);
      float bb[16];
#pragma unroll
      for (int K = 0; K < 2; ++K)
#pragma unroll
        for (int e = 0; e < 4; ++e) {
          // e' = e   (e'>>2 == 0): own half iff h==0
          bb[K * 8 + e]     = h ? s_[e + 4 + 8 * K] : (float)d[e + 8 * K];
          // e' = e+4 (e'>>2 == 1): own half iff h==1
          bb[K * 8 + e + 4] = h ? (float)d[e + 4 + 8 * K] : s_[e + 8 * K];
        }
      split8(bb,     bF[0], bF[1]);
      split8(bb + 8, bF[2], bF[3]);
    }
  }

  // D = (M_seg0*...*M_seg3)^T = P^T: d[e] = P^T[r][n], r=(e&3)+8(e>>2)+4h.
  // even seg -> buf = P^T row-major (A-side): pb[r*28+n] = d[e]
  // odd  seg -> buf = P row-major (B-side):   pb[n*28+r] = d[e] (f32x4 runs)
  float* pb = ws + (size_t)(batch * SEG + seg) * EMB;
  if (n < MD) {
    if ((seg & 1) == 0) {
#pragma unroll
      for (int e = 0; e < 16; ++e) {
        int r = (e & 3) + 8 * (e >> 2) + 4 * h;
        if (r < MD) pb[r * MD + n] = d[e];
      }
    } else {
#pragma unroll
      for (int q = 0; q < 4; ++q) {
        int r0 = 8 * q + 4 * h;
        if (r0 < MD) {
          f32x4 v = { d[4 * q], d[4 * q + 1], d[4 * q + 2], d[4 * q + 3] };
          *reinterpret_cast<f32x4*>(pb + n * MD + r0) = v;
        }
      }
    }
  }
}

// ---------------- kernel 2: tree-combine 16 partials (verified R6/R9) -----

__device__ __forceinline__ void kloop(const float* __restrict__ A,
                                      const float* __restrict__ B,
                                      int r0, int c0,
                                      f32x4& a0, f32x4& a1, f32x4& a2, f32x4& a3) {
  f32x4 z = {0.f, 0.f, 0.f, 0.f};
  a0 = a1 = a2 = a3 = z;
#pragma unroll
  for (int k = 0; k < MD; ++k) {
    f32x4 rv = *reinterpret_cast<const f32x4*>(A + k * MD + r0);
    f32x4 mv = *reinterpret_cast<const f32x4*>(B + k * MD + c0);
    a0 += rv[0] * mv;
    a1 += rv[1] * mv;
    a2 += rv[2] * mv;
    a3 += rv[3] * mv;
  }
}

__device__ __forceinline__ void store_T(float* __restrict__ D, int r0, int c0,
                                        const f32x4& a0, const f32x4& a1,
                                        const f32x4& a2, const f32x4& a3) {
#pragma unroll
  for (int cc = 0; cc < 4; ++cc) {
    f32x4 v = { a0[cc], a1[cc], a2[cc], a3[cc] };
    *reinterpret_cast<f32x4*>(D + (c0 + cc) * MD + r0) = v;
  }
}

__device__ __forceinline__ void store_N(float* __restrict__ D, int r0, int c0,
                                        const f32x4& a0, const f32x4& a1,
                                        const f32x4& a2, const f32x4& a3) {
  *reinterpret_cast<f32x4*>(D + (r0 + 0) * MD + c0) = a0;
  *reinterpret_cast<f32x4*>(D + (r0 + 1) * MD + c0) = a1;
  *reinterpret_cast<f32x4*>(D + (r0 + 2) * MD + c0) = a2;
  *reinterpret_cast<f32x4*>(D + (r0 + 3) * MD + c0) = a3;
}

__global__ __launch_bounds__(512, 1)
void w2m_combine(const float* __restrict__ ws, float* __restrict__ out) {
  __shared__ __align__(16) float P[SEG][EMB];
  __shared__ __align__(16) float Q8[8][EMB];
  __shared__ __align__(16) float Q4[4][EMB];
  __shared__ __align__(16) float Q2[2][EMB];

  const int batch = blockIdx.x;
  const int tid   = threadIdx.x;
  const int w     = tid >> 6;       // 0..7
  const int lane  = tid & 63;
  const bool act  = lane < 49;
  const int i = lane / 7, j = lane % 7;
  const int r0 = 4 * i, c0 = 4 * j;

  {
    const f32x4* src = reinterpret_cast<const f32x4*>(ws + (size_t)batch * SEG * EMB);
    f32x4* dst = reinterpret_cast<f32x4*>(&P[0][0]);
    for (int u = tid; u < SEG * EMB / 4; u += 512) dst[u] = src[u];
  }
  __syncthreads();

  f32x4 a0, a1, a2, a3;
  // level 0: Q8[w] = P[2w] * P[2w+1]   (8 waves)
  if (act) {
    kloop(P[2 * w], P[2 * w + 1], r0, c0, a0, a1, a2, a3);
    if (w & 1) store_N(Q8[w], r0, c0, a0, a1, a2, a3);
    else       store_T(Q8[w], r0, c0, a0, a1, a2, a3);
  }
  __syncthreads();
  // level 1: Q4[w] = Q8[2w] * Q8[2w+1]  (4 waves)
  if (w < 4 && act) {
    kloop(Q8[2 * w], Q8[2 * w + 1], r0, c0, a0, a1, a2, a3);
    if (w & 1) store_N(Q4[w], r0, c0, a0, a1, a2, a3);
    else       store_T(Q4[w], r0, c0, a0, a1, a2, a3);
  }
  __syncthreads();
  // level 2: Q2[w] = Q4[2w] * Q4[2w+1]  (2 waves)
  if (w < 2 && act) {
    kloop(Q4[2 * w], Q4[2 * w + 1], r0, c0, a0, a1, a2, a3);
    if (w & 1) store_N(Q2[w], r0, c0, a0, a1, a2, a3);
    else       store_T(Q2[w], r0, c0, a0, a1, a2, a3);
  }
  __syncthreads();
  // level 3: out = Q2[0] * Q2[1]
  if (w == 0 && act) {
    kloop(Q2[0], Q2[1], r0, c0, a0, a1, a2, a3);
    store_N(out + (size_t)batch * EMB, r0, c0, a0, a1, a2, a3);
  }
}

extern "C" void kernel_launch(void* const* d_in, const int* in_sizes, int n_in,
                              void* d_out, int out_size, void* d_ws, size_t ws_size,
                              hipStream_t stream) {
  const int*   sent = (const int*)d_in[0];    // (256, 64) int32
  const float* W    = (const float*)d_in[1];  // (30001, 784) f32
  float*       out  = (float*)d_out;          // (256, 784) f32
  float*       ws   = (float*)d_ws;           // 256*16*784*4 = 12.8 MB
  (void)in_sizes; (void)n_in; (void)out_size; (void)ws_size;

  w2m_partial_mfma<<<BATCH * SEG, 64, 0, stream>>>(sent, W, ws);
  w2m_combine<<<BATCH, 512, 0, stream>>>(ws, out);
}